// Round 17
// baseline (198.234 us; speedup 1.0000x reference)
//
#include <hip/hip_runtime.h>
#include <hip/hip_bf16.h>
#include <cmath>

#define NB 4
#define NS 1024
#define ND 1024
#define NH 16
#define NDH 64
#define NKSP 32
#define SCALE 0.125f      // 1/sqrt(64)
#define LOG2E 1.44269504f
#define SCALE2 (SCALE * LOG2E)

typedef __attribute__((ext_vector_type(8))) short bf16x8;
typedef __attribute__((ext_vector_type(4))) float f32x4;
typedef unsigned long long u64;

#define AS1 __attribute__((address_space(1)))
#define AS3 __attribute__((address_space(3)))

__device__ __forceinline__ void gl_lds16(const void* g, void* l) {
    __builtin_amdgcn_global_load_lds((const AS1 void*)g, (AS3 void*)l, 16, 0, 0);
}

__device__ __forceinline__ ushort f2bf(float f) {
    union { __hip_bfloat16 h; ushort u; } cv;
    cv.h = __float2bfloat16(f);
    return cv.u;
}
__device__ __forceinline__ float bf2f(ushort u) {
    union { unsigned int i; float f; } cv;
    cv.i = ((unsigned int)u) << 16;
    return cv.f;
}
__device__ __forceinline__ float fexp2(float x) {
    return __builtin_amdgcn_exp2f(x);   // v_exp_f32 (base-2)
}

// ---------------------------------------------------------------------------
// y=0: x->bf16 (4096 blocks); y=1..4: W->bf16 (1024 blocks);
// y=5: pack pmask into bitwords (4096 blocks, one wave per u64 word).
// ---------------------------------------------------------------------------
__global__ __launch_bounds__(256)
void f2bf_multi(const float* __restrict__ x,
                const float* __restrict__ w0, const float* __restrict__ w1,
                const float* __restrict__ w2, const float* __restrict__ w3,
                const int* __restrict__ pm,
                ushort* __restrict__ xo,
                ushort* __restrict__ o0, ushort* __restrict__ o1,
                ushort* __restrict__ o2, ushort* __restrict__ o3,
                u64* __restrict__ bm)
{
    int y = blockIdx.y;
    if (y == 5) {
        int word = blockIdx.x * 4 + (threadIdx.x >> 6);
        int lane = threadIdx.x & 63;
        int row  = word >> 4, wcol = word & 15;
        int v = pm[(size_t)row * NS + wcol * 64 + lane];
        u64 b = __ballot(v != 0);
        if (lane == 0) bm[word] = b;
        return;
    }
    const float* src; ushort* dst; int nblk;
    if (y == 0)      { src = x;  dst = xo; nblk = 4096; }
    else if (y == 1) { src = w0; dst = o0; nblk = 1024; }
    else if (y == 2) { src = w1; dst = o1; nblk = 1024; }
    else if (y == 3) { src = w2; dst = o2; nblk = 1024; }
    else             { src = w3; dst = o3; nblk = 1024; }
    if (blockIdx.x >= (unsigned)nblk) return;
    int i = (blockIdx.x * 256 + threadIdx.x) * 4;
    float4 v = *(const float4*)&src[i];
    ushort4 o;
    o.x = f2bf(v.x); o.y = f2bf(v.y); o.z = f2bf(v.z); o.w = f2bf(v.w);
    *(ushort4*)&dst[i] = o;
}

// ---------------------------------------------------------------------------
// Fused QKV GEMM. grid (24,32): blockIdx.x: [0,8)=Q [8,16)=K [16,24)=V.
// BK=64 (16 barrier pairs), row-XOR both-sides swizzle (rule #21):
// LDS chunk (row,sub) holds global chunk (row, sub^(row&7)); fragment
// read ck = (kk*4+quad) ^ (l16&7). LDS 32KB.
// ---------------------------------------------------------------------------
__global__ __launch_bounds__(256)
void gemm_qkv(const ushort* __restrict__ xb,
              const ushort* __restrict__ Wqb, const ushort* __restrict__ Wkb,
              const ushort* __restrict__ Wvb,
              const float* __restrict__ bq, const float* __restrict__ bk,
              const float* __restrict__ bv,
              ushort* __restrict__ Qo, ushort* __restrict__ Ko,
              ushort* __restrict__ Vo)
{
    constexpr int K = ND;
    __shared__ __attribute__((aligned(16))) ushort As[128 * 64];
    __shared__ __attribute__((aligned(16))) ushort Bs[128 * 64];

    const int tid  = threadIdx.x;
    const int lane = tid & 63, w = tid >> 6;
    const int wm = w >> 1, wn = w & 1;
    const int which = blockIdx.x >> 3;
    const int n0 = (blockIdx.x & 7) * 128;
    const int m0 = blockIdx.y * 128;
    const int quad = lane >> 4, l16 = lane & 15;

    const ushort* W = (which == 0) ? Wqb : (which == 1) ? Wkb : Wvb;
    const float* bias = (which == 0) ? bq : (which == 1) ? bk : bv;
    ushort* Out = (which == 0) ? Qo : (which == 1) ? Ko : Vo;

    f32x4 acc[4][4] = {};

    for (int k0 = 0; k0 < K; k0 += 64) {
        __syncthreads();
        // stage 128x64 A and B tiles (1024 chunks each; wave w: 256/tile)
#pragma unroll
        for (int u = 0; u < 4; ++u) {
            int cb = w * 256 + u * 64;
            int c  = cb + lane;
            int row = c >> 3, sub = c & 7;
            int kc = (sub ^ (row & 7)) * 8;       // source swizzle
            gl_lds16(xb + (size_t)(m0 + row) * K + k0 + kc, &As[cb * 8]);
            gl_lds16(W  + (size_t)(n0 + row) * K + k0 + kc, &Bs[cb * 8]);
        }
        __syncthreads();

        bf16x8 af[4][2], bfr[4][2];
#pragma unroll
        for (int mt = 0; mt < 4; ++mt) {
            int row = wm*64 + mt*16 + l16;        // row&7 == l16&7
#pragma unroll
            for (int kk = 0; kk < 2; ++kk) {
                int ck = (kk*4 + quad) ^ (l16 & 7);
                af[mt][kk] = *(const bf16x8*)&As[row*64 + ck*8];
            }
        }
#pragma unroll
        for (int nt = 0; nt < 4; ++nt) {
            int row = wn*64 + nt*16 + l16;
#pragma unroll
            for (int kk = 0; kk < 2; ++kk) {
                int ck = (kk*4 + quad) ^ (l16 & 7);
                bfr[nt][kk] = *(const bf16x8*)&Bs[row*64 + ck*8];
            }
        }
#pragma unroll
        for (int mt = 0; mt < 4; ++mt)
#pragma unroll
            for (int nt = 0; nt < 4; ++nt)
#pragma unroll
                for (int kk = 0; kk < 2; ++kk)
                    acc[mt][nt] = __builtin_amdgcn_mfma_f32_16x16x32_bf16(
                        af[mt][kk], bfr[nt][kk], acc[mt][nt], 0, 0, 0);
    }

#pragma unroll
    for (int nt = 0; nt < 4; ++nt) {
        int n = n0 + wn*64 + nt*16 + l16;
        float bz = bias[n];
        int hh = n >> 6, dh = n & 63;
#pragma unroll
        for (int mt = 0; mt < 4; ++mt) {
#pragma unroll
            for (int rg = 0; rg < 4; ++rg) {
                int m = m0 + wm*64 + mt*16 + quad*4 + rg;
                int b = m >> 10, s = m & (NS - 1);
                Out[(((size_t)(b*NH + hh))*NS + s)*NDH + dh] =
                    f2bf(acc[mt][nt][rg] + bz);
            }
        }
    }
}

// ---------------------------------------------------------------------------
// r17: transpose_v + attn_sparse MERGED into one dispatch. They are
// independent (sparse reads V not Vt; disjoint outputs) and complementary
// (transpose = BW-light streaming, sparse = gather-latency-bound), and
// unlike r13's failed fusion NEITHER PATH CHANGES: ids [0,1024) run the
// r12 transpose body, ids [1024, 1024+ns*1024) run the r12 sparse body,
// rest exit. Paths are block-uniform (no cross-path barrier hazard);
// LDS 8KB is transpose's only — sparse residency untaxed (r13's killer
// was taxing sparse with dense's LDS; absent here). Saves 1 launch gap
// + overlaps ~5us of transpose under ~13us of sparse.
// ---------------------------------------------------------------------------
__global__ __launch_bounds__(256)
void transv_sparse(const ushort* __restrict__ V, ushort* __restrict__ Vt,
                   const ushort* __restrict__ Qb, const ushort* __restrict__ Kb,
                   const int* __restrict__ pidx, const int* __restrict__ pimask,
                   const float* __restrict__ u_prev, ushort* __restrict__ OA)
{
    __shared__ __attribute__((aligned(16))) ushort T[64 * 64];

    const int id  = blockIdx.x;                   // grid 5120
    const int t   = threadIdx.x;
    const int lane = t & 63, w = t >> 6;

    if (id < 1024) {
        // ================== transpose path (r12 exact body) ==============
        const int bh = id >> 4;                   // 0..63 (b*16+h)
        const int st = id & 15;                   // s-tile
        const ushort* Vh  = V  + (size_t)bh * NS * NDH + (size_t)st * 64 * NDH;
        ushort*       Vth = Vt + (size_t)bh * NDH * NS + st * 64;

#pragma unroll
        for (int i = 0; i < 2; ++i) {
            int g = i * 256 + t;                  // 0..511
            int srow = g >> 3, sub = g & 7;
            union { bf16x8 v; ushort u[8]; } x;
            x.v = *(const bf16x8*)&Vh[(size_t)srow * NDH + sub * 8];
#pragma unroll
            for (int e = 0; e < 8; ++e) {
                int dh = sub * 8 + e;             // dh>>3 == sub
                T[dh*64 + (((srow >> 3) ^ sub) * 8) + (srow & 7)] = x.u[e];
            }
        }
        __syncthreads();
#pragma unroll
        for (int i = 0; i < 2; ++i) {
            int g = i * 256 + t;
            int dh = g >> 3, sc = g & 7;
            bf16x8 v = *(const bf16x8*)&T[dh*64 + ((sc ^ (dh >> 3)) * 8)];
            *(bf16x8*)&Vth[(size_t)dh * NS + sc * 8] = v;
        }
        return;
    }

    // ==================== sparse path (r12 exact body) ===================
    const int kj = lane >> 3;                     // key slot 0..7
    const int c  = lane & 7;                      // 16B chunk 0..7

    float lams[4];
#pragma unroll
    for (int i = 0; i < 4; ++i) lams[i] = 10.0f * __expf(-5.0f * u_prev[i]);
    int sl[4], ns = 0;
#pragma unroll
    for (int i = 0; i < 4; ++i) if (lams[i] >= 1.0f) sl[ns++] = i;

    const int sid = id - 1024;
    if (sid >= ns * 1024) return;                 // guard BEFORE %

    int xcd = sid & 7, j = sid >> 3;
    int nh2 = 2 * ns;
    int hi = j % nh2, qt = j / nh2;               // qt in [0,64)
    int gh = hi * 8 + xcd;
    const int b = sl[gh >> 4], h = gh & 15;
    const int s0 = qt * 16 + w * 4;

    const size_t bhh = (size_t)b * NH + h;
    const ushort* Qh = Qb + bhh * NS * NDH;
    const ushort* Kh = Kb + bhh * NS * NDH;
    const ushort* Vh = V  + bhh * NS * NDH;

    for (int r = 0; r < 4; ++r) {
        const int s = s0 + r;

        float qf[8];
        {
            union { bf16x8 v; ushort u[8]; } qv;
            qv.v = *(const bf16x8*)&Qh[(size_t)s * NDH + c * 8];
#pragma unroll
            for (int e = 0; e < 8; ++e) qf[e] = bf2f(qv.u[e]);
        }

        int kv[4], mv[4];
#pragma unroll
        for (int jj = 0; jj < 4; ++jj) {
            kv[jj] = pidx  [(size_t)s * NKSP + jj*8 + kj];
            mv[jj] = pimask[(size_t)s * NKSP + jj*8 + kj];
        }

        float sc[4];
#pragma unroll
        for (int jj = 0; jj < 4; ++jj) {
            union { bf16x8 v; ushort u[8]; } kc8;
            kc8.v = *(const bf16x8*)&Kh[(size_t)kv[jj] * NDH + c * 8];
            float d = 0.f;
#pragma unroll
            for (int e = 0; e < 8; ++e) d = fmaf(qf[e], bf2f(kc8.u[e]), d);
            d += __shfl_xor(d, 1);
            d += __shfl_xor(d, 2);
            d += __shfl_xor(d, 4);
            sc[jj] = mv[jj] ? d * SCALE : -INFINITY;
        }

        float mt = fmaxf(fmaxf(sc[0], sc[1]), fmaxf(sc[2], sc[3]));
        mt = fmaxf(mt, __shfl_xor(mt, 8));
        mt = fmaxf(mt, __shfl_xor(mt, 16));
        mt = fmaxf(mt, __shfl_xor(mt, 32));

        float p[4], psum = 0.f;
#pragma unroll
        for (int jj = 0; jj < 4; ++jj) {
            p[jj] = __expf(sc[jj] - mt);
            psum += p[jj];
        }
        psum += __shfl_xor(psum, 8);
        psum += __shfl_xor(psum, 16);
        psum += __shfl_xor(psum, 32);

        float o[8];
#pragma unroll
        for (int e = 0; e < 8; ++e) o[e] = 0.f;
#pragma unroll
        for (int jj = 0; jj < 4; ++jj) {
            union { bf16x8 v; ushort u[8]; } vc8;
            vc8.v = *(const bf16x8*)&Vh[(size_t)kv[jj] * NDH + c * 8];
#pragma unroll
            for (int e = 0; e < 8; ++e)
                o[e] = fmaf(p[jj], bf2f(vc8.u[e]), o[e]);
        }
#pragma unroll
        for (int e = 0; e < 8; ++e) {
            o[e] += __shfl_xor(o[e], 8);
            o[e] += __shfl_xor(o[e], 16);
            o[e] += __shfl_xor(o[e], 32);
        }

        if (kj == 0) {
            float inv = 1.f / psum;
            union { bf16x8 v; ushort u[8]; } ov;
#pragma unroll
            for (int e = 0; e < 8; ++e) ov.u[e] = f2bf(o[e] * inv);
            *(bf16x8*)&OA[((size_t)b*NS + s)*ND + h*NDH + c*8] = ov.v;
        }
    }
}

// ---------------------------------------------------------------------------
// Output GEMM: 64x128 tile -> 512 blocks. BK=64, row-XOR swizzle (r16).
// ---------------------------------------------------------------------------
__global__ __launch_bounds__(256)
void gemm_out(const ushort* __restrict__ A, const ushort* __restrict__ W,
              const float* __restrict__ bias, float* __restrict__ Cout)
{
    constexpr int K = ND;
    __shared__ __attribute__((aligned(16))) ushort As[64 * 64];
    __shared__ __attribute__((aligned(16))) ushort Bs[128 * 64];

    const int tid  = threadIdx.x;
    const int lane = tid & 63, w = tid >> 6;
    const int wm = w & 1, wn = w >> 1;
    const int m0 = blockIdx.y * 64, n0 = blockIdx.x * 128;
    const int quad = lane >> 4, l16 = lane & 15;

    f32x4 acc[2][4] = {};

    for (int k0 = 0; k0 < K; k0 += 64) {
        __syncthreads();
        // stage A: 64x64 tile = 512 chunks (2/thread)
#pragma unroll
        for (int u = 0; u < 2; ++u) {
            int cb = w * 128 + u * 64;
            int c  = cb + lane;
            int row = c >> 3, sub = c & 7;
            int kc = (sub ^ (row & 7)) * 8;       // source swizzle
            gl_lds16(A + (size_t)(m0 + row) * K + k0 + kc, &As[cb * 8]);
        }
        // stage B: 128x64 tile = 1024 chunks (4/thread)
#pragma unroll
        for (int u = 0; u < 4; ++u) {
            int cb = w * 256 + u * 64;
            int c  = cb + lane;
            int row = c >> 3, sub = c & 7;
            int kc = (sub ^ (row & 7)) * 8;
            gl_lds16(W + (size_t)(n0 + row) * K + k0 + kc, &Bs[cb * 8]);
        }
        __syncthreads();

        bf16x8 af[2][2], bfr[4][2];
#pragma unroll
        for (int mt = 0; mt < 2; ++mt) {
            int row = wm*32 + mt*16 + l16;        // row&7 == l16&7
#pragma unroll
            for (int kk = 0; kk < 2; ++kk) {
                int ck = (kk*4 + quad) ^ (l16 & 7);
                af[mt][kk] = *(const bf16x8*)&As[row*64 + ck*8];
            }
        }
#pragma unroll
        for (int nt = 0; nt < 4; ++nt) {
            int row = wn*64 + nt*16 + l16;
#pragma unroll
            for (int kk = 0; kk < 2; ++kk) {
                int ck = (kk*4 + quad) ^ (l16 & 7);
                bfr[nt][kk] = *(const bf16x8*)&Bs[row*64 + ck*8];
            }
        }
#pragma unroll
        for (int mt = 0; mt < 2; ++mt)
#pragma unroll
            for (int nt = 0; nt < 4; ++nt)
#pragma unroll
                for (int kk = 0; kk < 2; ++kk)
                    acc[mt][nt] = __builtin_amdgcn_mfma_f32_16x16x32_bf16(
                        af[mt][kk], bfr[nt][kk], acc[mt][nt], 0, 0, 0);
    }

#pragma unroll
    for (int nt = 0; nt < 4; ++nt) {
        int n = n0 + wn*64 + nt*16 + l16;
        float bz = bias[n];
#pragma unroll
        for (int mt = 0; mt < 2; ++mt) {
#pragma unroll
            for (int rg = 0; rg < 4; ++rg) {
                int m = m0 + wm*32 + mt*16 + quad*4 + rg;
                Cout[(size_t)m * ND + n] = acc[mt][nt][rg] + bz;
            }
        }
    }
}

// ---------------------------------------------------------------------------
// attn_dense (r12 exact): 32 q-rows/block, 4 waves = 4-way kt split,
// LDS-K staging + global-V, bm from L2, additive partials + LDS combine.
// ---------------------------------------------------------------------------
#define DSTAGE(T4)                                                            \
    _Pragma("unroll")                                                         \
    for (int u = 0; u < 8; ++u) {                                             \
        int cb = w * 512 + u * 64;                                            \
        int c  = cb + lane;                                                   \
        int tk = c >> 9, c2 = c & 511;                                        \
        int row = c2 >> 3, sub = c2 & 7;                                      \
        const ushort* src = Kh + (((size_t)(((T4)*4 + tk)*64 + row)) << 6)    \
                               + ((sub ^ (row & 7)) << 3);                    \
        gl_lds16(src, KK + (size_t)cb * 8);                                   \
    }

#define DLOADKV(KF, VF, KT)                                                   \
    _Pragma("unroll")                                                         \
    for (int nt = 0; nt < 4; ++nt)                                            \
        _Pragma("unroll")                                                     \
        for (int kk = 0; kk < 2; ++kk) {                                      \
            int rowk = nt*16 + l16;                                           \
            int ck = (kk*4 + quad) ^ (l16 & 7);                               \
            KF[nt][kk] = *(const bf16x8*)&KK[w*4096 + rowk*64 + ck*8];        \
            VF[nt][kk] = *(const bf16x8*)                                     \
                &Vth[(size_t)(nt*16 + l16) * NS + (KT)*64 + kk*32 + quad*8];  \
        }

#define DSTEP(KF, VF, M0, M1)                                                 \
    _Pragma("unroll")                                                         \
    for (int qh = 0; qh < 2; ++qh) {                                          \
        const int qrow = qh*16 + l16;                                         \
        u64 wqm = ((qh == 0) ? (M0) : (M1)) >> (quad * 4);                    \
        f32x4 s_acc[4] = {};                                                  \
        __builtin_amdgcn_s_setprio(1);                                        \
        _Pragma("unroll")                                                     \
        for (int nt = 0; nt < 4; ++nt)                                        \
            _Pragma("unroll")                                                 \
            for (int kk = 0; kk < 2; ++kk)                                    \
                s_acc[nt] = __builtin_amdgcn_mfma_f32_16x16x32_bf16(          \
                    KF[nt][kk], qf[qh][kk], s_acc[nt], 0, 0, 0);              \
        __builtin_amdgcn_s_setprio(0);                                        \
        _Pragma("unroll")                                                     \
        for (int nt = 0; nt < 4; ++nt) {                                      \
            ushort4 pk;                                                       \
            float p0 = fexp2(fmaf(s_acc[nt][0], SCALE2,                       \
                 ((wqm >> (nt*16 + 0)) & 1ULL) ? 0.f : nlam2));               \
            float p1 = fexp2(fmaf(s_acc[nt][1], SCALE2,                       \
                 ((wqm >> (nt*16 + 1)) & 1ULL) ? 0.f : nlam2));               \
            float p2 = fexp2(fmaf(s_acc[nt][2], SCALE2,                       \
                 ((wqm >> (nt*16 + 2)) & 1ULL) ? 0.f : nlam2));               \
            float p3 = fexp2(fmaf(s_acc[nt][3], SCALE2,                       \
                 ((wqm >> (nt*16 + 3)) & 1ULL) ? 0.f : nlam2));               \
            pk.x = f2bf(p0); pk.y = f2bf(p1);                                 \
            pk.z = f2bf(p2); pk.w = f2bf(p3);                                 \
            *(ushort4*)&Ps[w*2304 + qrow*72 + nt*16 + quad*4] = pk;           \
        }                                                                     \
        bf16x8 pf[2];                                                         \
        _Pragma("unroll")                                                     \
        for (int kk = 0; kk < 2; ++kk)                                        \
            pf[kk] = *(const bf16x8*)&Ps[w*2304 + qrow*72 + kk*32 + quad*8];  \
        __builtin_amdgcn_s_setprio(1);                                        \
        _Pragma("unroll")                                                     \
        for (int kk = 0; kk < 2; ++kk) {                                      \
            l_acc[qh] = __builtin_amdgcn_mfma_f32_16x16x32_bf16(              \
                pf[kk], ones.v, l_acc[qh], 0, 0, 0);                          \
            _Pragma("unroll")                                                 \
            for (int nt = 0; nt < 4; ++nt)                                    \
                o_acc[qh][nt] = __builtin_amdgcn_mfma_f32_16x16x32_bf16(      \
                    pf[kk], VF[nt][kk], o_acc[qh][nt], 0, 0, 0);              \
        }                                                                     \
        __builtin_amdgcn_s_setprio(0);                                        \
    }

__global__ __launch_bounds__(256)
void attn_dense(const ushort* __restrict__ Qb, const ushort* __restrict__ Kb,
                const ushort* __restrict__ Vt, const u64* __restrict__ bm,
                const float* __restrict__ u_prev, ushort* __restrict__ OA)
{
    __shared__ __attribute__((aligned(16))) ushort SM[25600];
    ushort* KK = SM;
    ushort* Ps = SM + 16384;

    const int tid  = threadIdx.x;
    const int lane = tid & 63, w = tid >> 6;
    const int quad = lane >> 4, l16 = lane & 15;

    float lams[4];
#pragma unroll
    for (int i = 0; i < 4; ++i) lams[i] = 10.0f * __expf(-5.0f * u_prev[i]);
    int dl[4], nd = 0;
#pragma unroll
    for (int i = 0; i < 4; ++i) if (lams[i] < 1.0f) dl[nd++] = i;

    const int id = blockIdx.x;                    // grid 2048
    if (id >= nd * 512) return;

    int xcd = id & 7, j = id >> 3;
    int nh2 = 2 * nd;
    int hi = j % nh2, qt = j / nh2;
    int gh = hi * 8 + xcd;
    const int b = dl[gh >> 4], h = gh & 15;
    const int s0 = qt * 32;
    const float nlam2 = -lams[b] * LOG2E;

    const size_t bh = (size_t)b * NH + h;
    const ushort* Qh  = Qb + bh * NS * NDH;
    const ushort* Kh  = Kb + bh * NS * NDH;
    const ushort* Vth = Vt + bh * NDH * NS;

    bf16x8 qf[2][2];
#pragma unroll
    for (int qh = 0; qh < 2; ++qh)
#pragma unroll
        for (int kk = 0; kk < 2; ++kk)
            qf[qh][kk] = *(const bf16x8*)
                &Qh[(size_t)(s0 + qh*16 + l16) * NDH + kk*32 + quad*8];

    union { bf16x8 v; ushort s[8]; } ones;
#pragma unroll
    for (int i = 0; i < 8; ++i) ones.s[i] = 0x3F80;

    f32x4 o_acc[2][4] = {};
    f32x4 l_acc[2] = {};

    for (int t = 0; t < 4; ++t) {
        if (t) __syncthreads();
        DSTAGE(t);
        const int kt = 4 * t + w;
        u64 m0 = bm[(size_t)(s0 +  0 + l16) * 16 + kt];
        u64 m1 = bm[(size_t)(s0 + 16 + l16) * 16 + kt];
        __syncthreads();
        bf16x8 kf[4][2], vf[4][2];
        DLOADKV(kf, vf, kt);
        DSTEP(kf, vf, m0, m1);
    }
    __syncthreads();

    float* POUT = (float*)SM;
    if (w != 0) {
        int base = (w - 1) * 2560;
#pragma unroll
        for (int qh = 0; qh < 2; ++qh) {
#pragma unroll
            for (int nt = 0; nt < 4; ++nt)
#pragma unroll
                for (int rg = 0; rg < 4; ++rg)
                    POUT[base + (qh*16 + nt*4 + rg)*64 + lane] =
                        o_acc[qh][nt][rg];
#pragma unroll
            for (int rg = 0; rg < 4; ++rg)
                POUT[base + (32 + qh*4 + rg)*64 + lane] = l_acc[qh][rg];
        }
    }
    __syncthreads();
    if (w == 0) {
#pragma unroll
        for (int s = 0; s < 3; ++s) {
            int base = s * 2560;
#pragma unroll
            for (int qh = 0; qh < 2; ++qh) {
#pragma unroll
                for (int nt = 0; nt < 4; ++nt)
#pragma unroll
                    for (int rg = 0; rg < 4; ++rg)
                        o_acc[qh][nt][rg] +=
                            POUT[base + (qh*16 + nt*4 + rg)*64 + lane];
#pragma unroll
                for (int rg = 0; rg < 4; ++rg)
                    l_acc[qh][rg] += POUT[base + (32 + qh*4 + rg)*64 + lane];
            }
        }
#pragma unroll
        for (int qh = 0; qh < 2; ++qh) {
            float inv[4];
#pragma unroll
            for (int rg = 0; rg < 4; ++rg) inv[rg] = 1.f / l_acc[qh][rg];
#pragma unroll
            for (int nt = 0; nt < 4; ++nt)
#pragma unroll
                for (int rg = 0; rg < 4; ++rg) {
                    int m = qh*16 + quad*4 + rg;
                    OA[((size_t)b*NS + s0 + m)*ND + h*NDH + nt*16 + l16] =
                        f2bf(o_acc[qh][nt][rg] * inv[rg]);
                }
        }
    }
}

// ---------------------------------------------------------------------------
extern "C" void kernel_launch(void* const* d_in, const int* in_sizes, int n_in,
                              void* d_out, int out_size, void* d_ws, size_t ws_size,
                              hipStream_t stream)
{
    const float* x      = (const float*)d_in[0];
    const int*   pmask  = (const int*)  d_in[1];
    const int*   pidx   = (const int*)  d_in[2];
    const int*   pimask = (const int*)  d_in[3];
    const float* u_prev = (const float*)d_in[4];
    const float* Wq     = (const float*)d_in[5];
    const float* bq     = (const float*)d_in[6];
    const float* Wk     = (const float*)d_in[7];
    const float* bk     = (const float*)d_in[8];
    const float* Wv     = (const float*)d_in[9];
    const float* bv     = (const float*)d_in[10];
    const float* Wo     = (const float*)d_in[11];
    const float* bo     = (const float*)d_in[12];
    float* out = (float*)d_out;

    const size_t QSZ = (size_t)NB * NH * NS * NDH;   // 4,194,304 elements
    const size_t WSZ = (size_t)ND * ND;              // 1,048,576 elements
    ushort* xb  = (ushort*)d_ws;        // bf16 x              (8 MB)
    ushort* Qw  = xb  + QSZ;            // bf16 Q (b,h,s,dh)   (8 MB)
    ushort* Kw  = Qw  + QSZ;            // bf16 K              (8 MB)
    ushort* Vw  = Kw  + QSZ;            // bf16 V              (8 MB)
    ushort* Vtw = Vw  + QSZ;            // bf16 V^T (b,h,dh,s) (8 MB)
    ushort* Awb = Vtw + QSZ;            // bf16 attn out       (8 MB)
    ushort* Wqb = Awb + QSZ;            // bf16 weights (2 MB each)
    ushort* Wkb = Wqb + WSZ;
    ushort* Wvb = Wkb + WSZ;
    ushort* Wob = Wvb + WSZ;
    u64*    bmw = (u64*)(Wob + WSZ);    // packed mask (128 KB)

    f2bf_multi<<<dim3(4096, 6), 256, 0, stream>>>(
        x, Wq, Wk, Wv, Wo, pmask, xb, Wqb, Wkb, Wvb, Wob, bmw);

    gemm_qkv<<<dim3(24, 32), 256, 0, stream>>>(
        xb, Wqb, Wkb, Wvb, bq, bk, bv, Qw, Kw, Vw);

    transv_sparse<<<5120, 256, 0, stream>>>(
        Vw, Vtw, Qw, Kw, pidx, pimask, u_prev, Awb);

    attn_dense<<<2048, 256, 0, stream>>>(
        Qw, Kw, Vtw, bmw, u_prev, Awb);

    gemm_out<<<dim3(ND/128, (NB*NS)/64), 256, 0, stream>>>(Awb, Wob, bo, out);
}